// Round 8
// baseline (544.526 us; speedup 1.0000x reference)
//
#include <hip/hip_runtime.h>
#include <math.h>

// Problem constants
#define BATCH 128
#define NPER 400
#define EPG 6400
#define NEDGE 819200
#define F_IN 400
#define HD 128
#define K1 320
#define K2 256
#define K3 205

typedef __bf16 bf16x8 __attribute__((ext_vector_type(8)));
typedef float f32x4 __attribute__((ext_vector_type(4)));

__device__ __forceinline__ unsigned short f2bf(float f) {
    unsigned u = __builtin_bit_cast(unsigned, f);
    unsigned r = u + 0x7fffu + ((u >> 16) & 1u);
    return (unsigned short)(r >> 16);
}
__device__ __forceinline__ float bf2f(unsigned short s) {
    unsigned u = ((unsigned)s) << 16;
    return __builtin_bit_cast(float, u);
}

// ---------------- workspace layout ----------------
static constexpr size_t SZ_TREL = 51200ull * 128 * 4;
static constexpr size_t OFF_TREL = 0;
static constexpr size_t OFF_H    = OFF_TREL + SZ_TREL;
static constexpr size_t OFF_HP   = OFF_H + SZ_TREL;
static constexpr size_t OFF_SC   = OFF_HP + 40960ull * 128 * 4;
static constexpr size_t OFF_IDX  = OFF_SC + 51200ull * 4;
static constexpr size_t OFF_VALS = OFF_IDX + 40960ull * 4;
static constexpr size_t OFF_NEWID= OFF_VALS + 40960ull * 4;
static constexpr size_t OFF_ES   = OFF_NEWID + 51200ull * 4;
static constexpr size_t OFF_ED   = OFF_ES + (size_t)NEDGE * 4;
static constexpr size_t OFF_EM   = OFF_ED + (size_t)NEDGE * 4;
static constexpr size_t OFF_Z    = OFF_EM + (size_t)NEDGE * 4;
static constexpr size_t OFF_COFF = OFF_Z + 128ull * 256 * 4;
static constexpr size_t OFF_CDEG = OFF_COFF + 51200ull * 4;
static constexpr size_t OFF_CSRC = OFF_CDEG + 51200ull * 4;
static constexpr size_t OFF_W1H  = OFF_CSRC + (size_t)NEDGE * 4;   // 16*13*512 shorts
static constexpr size_t OFF_W1L  = OFF_W1H + 16ull * 13 * 512 * 2;
static constexpr size_t OFF_W2H  = OFF_W1L + 16ull * 13 * 512 * 2;
static constexpr size_t OFF_W2L  = OFF_W2H + 16ull * 4 * 512 * 2;
static constexpr size_t OFF_W3H  = OFF_W2L + 16ull * 4 * 512 * 2;
static constexpr size_t OFF_W3L  = OFF_W3H + 16ull * 4 * 512 * 2;

// ---------------- weight split + fragment-tile prep (all 3 layers) ---------
// Tiled layout: chunk[(n_tile*Ks + s)*512 + (qd*16 + rowin)*8 + e] holds
// B[n_tile*16+rowin][s*32 + qd*8 + e] -- exactly the per-lane MFMA B-fragment
// order, so GEMM B loads are lane-linear (coalesced 1KB per wave instr).
__global__ __launch_bounds__(64) void prep_w_all(
    const float* __restrict__ Wrel1, const float* __restrict__ Wroot1,
    const float* __restrict__ Wrel2, const float* __restrict__ Wroot2,
    const float* __restrict__ Wrel3, const float* __restrict__ Wroot3,
    unsigned short* __restrict__ b1h, unsigned short* __restrict__ b1l,
    unsigned short* __restrict__ b2h, unsigned short* __restrict__ b2l,
    unsigned short* __restrict__ b3h, unsigned short* __restrict__ b3l) {
    const int layer = blockIdx.z;
    const int s = blockIdx.x;
    const int ntile = blockIdx.y;
    const int Ks = (layer == 0) ? 13 : 4;
    const int Kd = (layer == 0) ? F_IN : HD;
    if (s >= Ks) return;
    const float* Wrel  = (layer == 0) ? Wrel1  : (layer == 1) ? Wrel2  : Wrel3;
    const float* Wroot = (layer == 0) ? Wroot1 : (layer == 1) ? Wroot2 : Wroot3;
    unsigned short* bh = (layer == 0) ? b1h : (layer == 1) ? b2h : b3h;
    unsigned short* bl = (layer == 0) ? b1l : (layer == 1) ? b2l : b3l;
    const int t = threadIdx.x;
    const int rowin = t & 15, qd = t >> 4;
    const int n = ntile * 16 + rowin;
    const int k = s * 32 + qd * 8;
    const float* src = (n < 128) ? &Wrel[(n & 127) * Kd] : &Wroot[(n & 127) * Kd];
    unsigned short hv[8], lv[8];
#pragma unroll
    for (int e = 0; e < 8; e++) {
        float f = (k + e < Kd) ? src[k + e] : 0.f;
        unsigned short hi = f2bf(f);
        hv[e] = hi;
        lv[e] = f2bf(f - bf2f(hi));
    }
    size_t o = ((size_t)ntile * Ks + s) * 512 + (size_t)t * 8;
#pragma unroll
    for (int e = 0; e < 8; e++) { bh[o + e] = hv[e]; bl[o + e] = lv[e]; }
}

// ---------------- MFMA GEMM (bf16x3 split, NO LDS, NO barriers) ------------
// A fp32 [M][Kd] row-major: a lane's MFMA A-fragment is 8 contiguous k-elems
// of one row -> direct 32B global load + in-register hi/lo bf16 split.
// B from pre-tiled planes (coalesced lane-linear loads, L2-resident).
// Block = 256 thr / 4 waves; wave w = 64 rows x 64 cols (n-tiles w*4..w*4+3);
// cols 0-127 -> t_rel, 128-255 -> h. Grid = M/64.
__global__ __launch_bounds__(256) void gemm_mfma(
    const float* __restrict__ A,
    const unsigned short* __restrict__ bh_p, const unsigned short* __restrict__ bl_p,
    float* __restrict__ t_rel, float* __restrict__ h, int Kd, int Ks) {
    const int tid = threadIdx.x;
    const int lane = tid & 63;
    const int wid = tid >> 6;
    const int lm = lane & 15;
    const int qd = lane >> 4;
    const int m0 = blockIdx.x * 64;
    const int nt0 = wid * 4;

    f32x4 acc[4][4];
#pragma unroll
    for (int i = 0; i < 4; i++)
#pragma unroll
        for (int j = 0; j < 4; j++) acc[i][j] = (f32x4){0.f, 0.f, 0.f, 0.f};

    const float* Abase = A + (size_t)(m0 + lm) * Kd + qd * 8;

    for (int s = 0; s < Ks; s++) {
        const int kq = s * 32 + qd * 8;
        // ---- A: direct fp32 frag loads + in-register split ----
        bf16x8 ah[4], al[4];
#pragma unroll
        for (int i = 0; i < 4; i++) {
            float4 f0, f1;
            if (kq < Kd) {
                const float* p = Abase + (size_t)i * 16 * Kd + s * 32;
                f0 = *(const float4*)p;
                f1 = *(const float4*)(p + 4);
            } else {
                f0 = make_float4(0.f, 0.f, 0.f, 0.f);
                f1 = f0;
            }
            float fe[8] = {f0.x, f0.y, f0.z, f0.w, f1.x, f1.y, f1.z, f1.w};
#pragma unroll
            for (int e = 0; e < 8; e++) {
                __bf16 hb = (__bf16)fe[e];
                ah[i][e] = hb;
                al[i][e] = (__bf16)(fe[e] - (float)hb);
            }
        }
        // ---- B: coalesced tiled frag loads ----
        bf16x8 bh[4], bl[4];
#pragma unroll
        for (int j = 0; j < 4; j++)
            bh[j] = *(const bf16x8*)&bh_p[((size_t)(nt0 + j) * Ks + s) * 512 + lane * 8];
#pragma unroll
        for (int j = 0; j < 4; j++)
            bl[j] = *(const bf16x8*)&bl_p[((size_t)(nt0 + j) * Ks + s) * 512 + lane * 8];
        // ---- MFMA: hi*hi + lo*hi + hi*lo ----
#pragma unroll
        for (int j = 0; j < 4; j++)
#pragma unroll
            for (int i = 0; i < 4; i++)
                acc[i][j] = __builtin_amdgcn_mfma_f32_16x16x32_bf16(
                    ah[i], bh[j], acc[i][j], 0, 0, 0);
#pragma unroll
        for (int j = 0; j < 4; j++)
#pragma unroll
            for (int i = 0; i < 4; i++)
                acc[i][j] = __builtin_amdgcn_mfma_f32_16x16x32_bf16(
                    al[i], bh[j], acc[i][j], 0, 0, 0);
#pragma unroll
        for (int j = 0; j < 4; j++)
#pragma unroll
            for (int i = 0; i < 4; i++)
                acc[i][j] = __builtin_amdgcn_mfma_f32_16x16x32_bf16(
                    ah[i], bl[j], acc[i][j], 0, 0, 0);
    }
    // ---- epilogue: C/D layout col=lane&15, row=qd*4+reg ----
    float* out = (wid < 2) ? t_rel : h;
    const int colbase = (wid & 1) * 64;
#pragma unroll
    for (int i = 0; i < 4; i++)
#pragma unroll
        for (int j = 0; j < 4; j++) {
            int row = m0 + i * 16 + qd * 4;
            int col = colbase + j * 16 + lm;
#pragma unroll
            for (int r = 0; r < 4; r++)
                out[(size_t)(row + r) * 128 + col] = acc[i][j][r];
        }
}

// ---------------- CSR build for layer 1 (original edges, no mask) ----------
__global__ __launch_bounds__(1024) void csr_build0(
    const int* __restrict__ gsrc, const int* __restrict__ gdst,
    int* __restrict__ csr_off, int* __restrict__ csr_deg, int* __restrict__ csr_src) {
    __shared__ int cnt[NPER];
    __shared__ int cur[NPER];
    __shared__ int sscan[512];
    const int g = blockIdx.x;
    const int t = threadIdx.x;
    for (int i = t; i < NPER; i += 1024) cnt[i] = 0;
    __syncthreads();
    for (int e = t; e < EPG; e += 1024) {
        int dl = gdst[g * EPG + e] - g * NPER;
        atomicAdd(&cnt[dl], 1);
    }
    __syncthreads();
    if (t < 512) sscan[t] = (t < NPER) ? cnt[t] : 0;
    __syncthreads();
    for (int d = 1; d < 512; d <<= 1) {
        int v = 0;
        if (t < 512 && t >= d) v = sscan[t - d];
        __syncthreads();
        if (t < 512 && t >= d) sscan[t] += v;
        __syncthreads();
    }
    if (t < NPER) {
        int excl = (t == 0) ? 0 : sscan[t - 1];
        int st = g * EPG + excl;
        csr_off[g * NPER + t] = st;
        csr_deg[g * NPER + t] = cnt[t];
        cur[t] = st;
    }
    __syncthreads();
    for (int e = t; e < EPG; e += 1024) {
        int eg = g * EPG + e;
        int dl = gdst[eg] - g * NPER;
        int slot = atomicAdd(&cur[dl], 1);
        csr_src[slot] = gsrc[eg];
    }
}

// ---------------- fused edge remap + CSR build (layers 2,3 conv prep) -------
__global__ __launch_bounds__(1024) void csr_remap(
    const int* __restrict__ es_in, const int* __restrict__ ed_in,
    const int* __restrict__ em_in,
    const int* __restrict__ gsrc, const int* __restrict__ gdst,
    const int* __restrict__ newid,
    int* __restrict__ es_out, int* __restrict__ ed_out, int* __restrict__ em_out,
    int* __restrict__ csr_off, int* __restrict__ csr_deg, int* __restrict__ csr_src,
    int npg_prev, int k, int first) {
    __shared__ int nid[NPER];
    __shared__ int packed[EPG];
    __shared__ int cnt[K1];
    __shared__ int cur[K1];
    __shared__ int sscan[512];
    const int g = blockIdx.x;
    const int t = threadIdx.x;
    for (int i = t; i < npg_prev; i += 1024) nid[i] = newid[g * npg_prev + i];
    for (int i = t; i < k; i += 1024) cnt[i] = 0;
    __syncthreads();
    for (int e = t; e < EPG; e += 1024) {
        int eg = g * EPG + e;
        int sl, dl, m;
        if (first) { sl = gsrc[eg] - g * NPER; dl = gdst[eg] - g * NPER; m = 1; }
        else       { sl = es_in[eg]; dl = ed_in[eg]; m = em_in[eg]; }
        int ns = nid[sl], nd = nid[dl];
        int keep = (m && ns >= 0 && nd >= 0) ? 1 : 0;
        es_out[eg] = keep ? ns : 0;
        ed_out[eg] = keep ? nd : 0;
        em_out[eg] = keep;
        packed[e] = keep ? (ns | (nd << 16)) : -1;
        if (keep) atomicAdd(&cnt[nd], 1);
    }
    __syncthreads();
    if (t < 512) sscan[t] = (t < k) ? cnt[t] : 0;
    __syncthreads();
    for (int d = 1; d < 512; d <<= 1) {
        int v = 0;
        if (t < 512 && t >= d) v = sscan[t - d];
        __syncthreads();
        if (t < 512 && t >= d) sscan[t] += v;
        __syncthreads();
    }
    if (t < k) {
        int excl = (t == 0) ? 0 : sscan[t - 1];
        int st = g * EPG + excl;
        csr_off[g * k + t] = st;
        csr_deg[g * k + t] = cnt[t];
        cur[t] = st;
    }
    __syncthreads();
    for (int e = t; e < EPG; e += 1024) {
        int p = packed[e];
        if (p >= 0) {
            int ns = p & 0xffff, nd = p >> 16;
            int slot = atomicAdd(&cur[nd], 1);
            csr_src[slot] = g * k + ns;
        }
    }
}

// ---------------- Aggregation (gather) + combine + relu + score ------------
__global__ __launch_bounds__(256) void agg_score(
    const float* __restrict__ t_rel,
    const int* __restrict__ csr_off, const int* __restrict__ csr_deg,
    const int* __restrict__ csr_src,
    const float* __restrict__ bias, const float* __restrict__ pw,
    float* __restrict__ h, float* __restrict__ sc, int npg) {
    const int xcd = blockIdx.x & 7;
    const int j = blockIdx.x >> 3;
    const int bpg = npg >> 2;
    const int graph = xcd * (BATCH / 8) + j / bpg;
    const int nblk = j - (j / bpg) * bpg;
    const int wid = graph * npg + nblk * 4 + (threadIdx.x >> 6);
    const int lane = threadIdx.x & 63;

    const int start = csr_off[wid];
    const int deg = csr_deg[wid];
    const size_t fo = (size_t)lane * 2;
    float a0 = 0.f, a1 = 0.f, b0 = 0.f, b1 = 0.f;
    float c0 = 0.f, c1 = 0.f, d0 = 0.f, d1 = 0.f;
    int e = 0;
    for (; e + 4 <= deg; e += 4) {
        int s0 = csr_src[start + e];
        int s1 = csr_src[start + e + 1];
        int s2 = csr_src[start + e + 2];
        int s3 = csr_src[start + e + 3];
        float2 v0 = *(const float2*)&t_rel[(size_t)s0 * 128 + fo];
        float2 v1 = *(const float2*)&t_rel[(size_t)s1 * 128 + fo];
        float2 v2 = *(const float2*)&t_rel[(size_t)s2 * 128 + fo];
        float2 v3 = *(const float2*)&t_rel[(size_t)s3 * 128 + fo];
        a0 += v0.x; a1 += v0.y;
        b0 += v1.x; b1 += v1.y;
        c0 += v2.x; c1 += v2.y;
        d0 += v3.x; d1 += v3.y;
    }
    for (; e < deg; e++) {
        int s0 = csr_src[start + e];
        float2 v0 = *(const float2*)&t_rel[(size_t)s0 * 128 + fo];
        a0 += v0.x; a1 += v0.y;
    }
    a0 += b0 + c0 + d0;
    a1 += b1 + c1 + d1;

    float2 bb = *(const float2*)&bias[fo];
    size_t o = (size_t)wid * 128 + fo;
    float2 hv = *(const float2*)&h[o];
    hv.x = fmaxf(hv.x + a0 + bb.x, 0.f);
    hv.y = fmaxf(hv.y + a1 + bb.y, 0.f);
    *(float2*)&h[o] = hv;
    float2 pp = *(const float2*)&pw[fo];
    float d = hv.x * pp.x + hv.y * pp.y;
    float nr = pp.x * pp.x + pp.y * pp.y;
#pragma unroll
    for (int off = 32; off; off >>= 1) {
        d += __shfl_down(d, off, 64);
        nr += __shfl_down(nr, off, 64);
    }
    if (lane == 0) sc[wid] = d / (sqrtf(nr) + 1e-16f);
}

// ---------------- topk per graph: exact bitonic sort of 512 ----------------
__device__ __forceinline__ bool rank_before(float as, int ai, float bs, int bi) {
    return (as > bs) || (as == bs && ai < bi);
}
__global__ __launch_bounds__(256) void topk_kernel(const float* __restrict__ sc,
                                                   int* __restrict__ idxo,
                                                   float* __restrict__ valso,
                                                   int* __restrict__ newid,
                                                   int npg, int k) {
    __shared__ float sk[512];
    __shared__ int si[512];
    const int g = blockIdx.x;
    for (int t = threadIdx.x; t < 512; t += 256) {
        sk[t] = (t < npg) ? sc[g * npg + t] : -INFINITY;
        si[t] = t;
    }
    __syncthreads();
    for (int size = 2; size <= 512; size <<= 1) {
        for (int stride = size >> 1; stride; stride >>= 1) {
            for (int i = threadIdx.x; i < 512; i += 256) {
                int j = i ^ stride;
                if (j > i) {
                    bool up = ((i & size) == 0);
                    float a = sk[i], b = sk[j];
                    int ai = si[i], bi = si[j];
                    bool doswap = up ? rank_before(b, bi, a, ai)
                                     : rank_before(a, ai, b, bi);
                    if (doswap) { sk[i] = b; sk[j] = a; si[i] = bi; si[j] = ai; }
                }
            }
            __syncthreads();
        }
    }
    for (int t = threadIdx.x; t < 512; t += 256) {
        if (t < npg) {
            int orig = si[t];
            newid[g * npg + orig] = (t < k) ? t : -1;
            if (t < k) { idxo[g * k + t] = orig; valso[g * k + t] = sk[t]; }
        }
    }
}

// ---------------- fused gather+gate+(hp write)+readout ----------------
__global__ __launch_bounds__(512) void pool_readout(
    const float* __restrict__ h, const int* __restrict__ idx,
    const float* __restrict__ vals, float* __restrict__ hp,
    float* __restrict__ z, int npg, int k) {
    __shared__ float tg[K1];
    __shared__ int ix[K1];
    __shared__ float pmx[4][128], psm[4][128];
    const int g = blockIdx.x;
    const int f = threadIdx.x & 127;
    const int jq = threadIdx.x >> 7;
    for (int j = threadIdx.x; j < k; j += 512) {
        tg[j] = tanhf(vals[g * k + j]);
        ix[j] = idx[g * k + j];
    }
    __syncthreads();
    float mx = -INFINITY, sm = 0.f;
    for (int j = jq; j < k; j += 4) {
        float v = h[(size_t)(g * npg + ix[j]) * 128 + f] * tg[j];
        if (hp) hp[(size_t)(g * k + j) * 128 + f] = v;
        mx = fmaxf(mx, v);
        sm += v;
    }
    pmx[jq][f] = mx; psm[jq][f] = sm;
    __syncthreads();
    if (threadIdx.x < 128) {
        mx = fmaxf(fmaxf(pmx[0][f], pmx[1][f]), fmaxf(pmx[2][f], pmx[3][f]));
        sm = psm[0][f] + psm[1][f] + psm[2][f] + psm[3][f];
        z[g * 256 + f] += mx;
        z[g * 256 + 128 + f] += sm / (float)k;
    }
}

// ---------------- MLP head + log_softmax ----------------
__global__ __launch_bounds__(256) void mlp_head(const float* __restrict__ z,
                                                const float* __restrict__ W1,
                                                const float* __restrict__ bl1,
                                                const float* __restrict__ W2,
                                                const float* __restrict__ bl2,
                                                const float* __restrict__ W3,
                                                const float* __restrict__ bl3,
                                                float* __restrict__ out) {
    __shared__ float zs[256], l1[128], l2[64];
    const int g = blockIdx.x, t = threadIdx.x;
    zs[t] = z[g * 256 + t];
    __syncthreads();
    if (t < 128) {
        float s = bl1[t];
        const float* w = &W1[t * 256];
        for (int i = 0; i < 256; i++) s += w[i] * zs[i];
        l1[t] = fmaxf(s, 0.f);
    }
    __syncthreads();
    if (t < 64) {
        float s = bl2[t];
        const float* w = &W2[t * 128];
        for (int i = 0; i < 128; i++) s += w[i] * l1[i];
        l2[t] = fmaxf(s, 0.f);
    }
    __syncthreads();
    if (t == 0) {
        float a = bl3[0], b = bl3[1];
        for (int i = 0; i < 64; i++) { a += W3[i] * l2[i]; b += W3[64 + i] * l2[i]; }
        float m = fmaxf(a, b);
        float lse = m + logf(expf(a - m) + expf(b - m));
        out[g * 2 + 0] = a - lse;
        out[g * 2 + 1] = b - lse;
    }
}

// ---------------- launch ----------------
extern "C" void kernel_launch(void* const* d_in, const int* in_sizes, int n_in,
                              void* d_out, int out_size, void* d_ws, size_t ws_size,
                              hipStream_t stream) {
    const float* x        = (const float*)d_in[0];
    const int*   edge_src = (const int*)d_in[1];
    const int*   edge_dst = (const int*)d_in[2];
    const float* Wrel1 = (const float*)d_in[4];
    const float* Wroot1= (const float*)d_in[5];
    const float* b1    = (const float*)d_in[6];
    const float* pw1   = (const float*)d_in[7];
    const float* Wrel2 = (const float*)d_in[8];
    const float* Wroot2= (const float*)d_in[9];
    const float* b2    = (const float*)d_in[10];
    const float* pw2   = (const float*)d_in[11];
    const float* Wrel3 = (const float*)d_in[12];
    const float* Wroot3= (const float*)d_in[13];
    const float* b3    = (const float*)d_in[14];
    const float* pw3   = (const float*)d_in[15];
    const float* W1    = (const float*)d_in[16];
    const float* bl1   = (const float*)d_in[17];
    const float* W2    = (const float*)d_in[18];
    const float* bl2   = (const float*)d_in[19];
    const float* W3    = (const float*)d_in[20];
    const float* bl3   = (const float*)d_in[21];

    char* ws = (char*)d_ws;
    float* t_rel = (float*)(ws + OFF_TREL);
    float* h     = (float*)(ws + OFF_H);
    float* hp    = (float*)(ws + OFF_HP);
    float* sc    = (float*)(ws + OFF_SC);
    int*   idx   = (int*)(ws + OFF_IDX);
    float* vals  = (float*)(ws + OFF_VALS);
    int*   newid = (int*)(ws + OFF_NEWID);
    int*   es    = (int*)(ws + OFF_ES);
    int*   ed    = (int*)(ws + OFF_ED);
    int*   em    = (int*)(ws + OFF_EM);
    float* z     = (float*)(ws + OFF_Z);
    int*   coff  = (int*)(ws + OFF_COFF);
    int*   cdeg  = (int*)(ws + OFF_CDEG);
    int*   csrc  = (int*)(ws + OFF_CSRC);
    unsigned short* w1h = (unsigned short*)(ws + OFF_W1H);
    unsigned short* w1l = (unsigned short*)(ws + OFF_W1L);
    unsigned short* w2h = (unsigned short*)(ws + OFF_W2H);
    unsigned short* w2l = (unsigned short*)(ws + OFF_W2L);
    unsigned short* w3h = (unsigned short*)(ws + OFF_W3H);
    unsigned short* w3l = (unsigned short*)(ws + OFF_W3L);

    hipMemsetAsync(z, 0, 128ull * 256 * 4, stream);
    prep_w_all<<<dim3(13, 16, 3), 64, 0, stream>>>(
        Wrel1, Wroot1, Wrel2, Wroot2, Wrel3, Wroot3,
        w1h, w1l, w2h, w2l, w3h, w3l);
    csr_build0<<<BATCH, 1024, 0, stream>>>(edge_src, edge_dst, coff, cdeg, csrc);

    // ---------- layer 1 ----------
    gemm_mfma<<<800, 256, 0, stream>>>(x, w1h, w1l, t_rel, h, F_IN, 13);
    agg_score<<<51200 / 4, 256, 0, stream>>>(t_rel, coff, cdeg, csrc, b1, pw1,
                                             h, sc, NPER);
    topk_kernel<<<BATCH, 256, 0, stream>>>(sc, idx, vals, newid, NPER, K1);
    csr_remap<<<BATCH, 1024, 0, stream>>>(nullptr, nullptr, nullptr,
                                          edge_src, edge_dst, newid,
                                          es, ed, em, coff, cdeg, csrc,
                                          NPER, K1, 1);
    pool_readout<<<BATCH, 512, 0, stream>>>(h, idx, vals, hp, z, NPER, K1);

    // ---------- layer 2 ----------
    gemm_mfma<<<640, 256, 0, stream>>>(hp, w2h, w2l, t_rel, h, HD, 4);
    agg_score<<<40960 / 4, 256, 0, stream>>>(t_rel, coff, cdeg, csrc, b2, pw2,
                                             h, sc, K1);
    topk_kernel<<<BATCH, 256, 0, stream>>>(sc, idx, vals, newid, K1, K2);
    csr_remap<<<BATCH, 1024, 0, stream>>>(es, ed, em, nullptr, nullptr, newid,
                                          es, ed, em, coff, cdeg, csrc,
                                          K1, K2, 0);
    pool_readout<<<BATCH, 512, 0, stream>>>(h, idx, vals, hp, z, K1, K2);

    // ---------- layer 3 ----------
    gemm_mfma<<<512, 256, 0, stream>>>(hp, w3h, w3l, t_rel, h, HD, 4);
    agg_score<<<32768 / 4, 256, 0, stream>>>(t_rel, coff, cdeg, csrc, b3, pw3,
                                             h, sc, K2);
    topk_kernel<<<BATCH, 256, 0, stream>>>(sc, idx, vals, newid, K2, K3);
    pool_readout<<<BATCH, 512, 0, stream>>>(h, idx, vals, nullptr, z, K2, K3);

    // ---------- MLP head ----------
    mlp_head<<<BATCH, 256, 0, stream>>>(z, W1, bl1, W2, bl2, W3, bl3, (float*)d_out);
}

// Round 9
// 499.667 us; speedup vs baseline: 1.0898x; 1.0898x over previous
//
#include <hip/hip_runtime.h>
#include <math.h>

// Problem constants
#define BATCH 128
#define NPER 400
#define EPG 6400
#define NEDGE 819200
#define F_IN 400
#define HD 128
#define K1 320
#define K2 256
#define K3 205

typedef __bf16 bf16x8 __attribute__((ext_vector_type(8)));
typedef float f32x4 __attribute__((ext_vector_type(4)));

__device__ __forceinline__ unsigned short f2bf(float f) {
    unsigned u = __builtin_bit_cast(unsigned, f);
    unsigned r = u + 0x7fffu + ((u >> 16) & 1u);
    return (unsigned short)(r >> 16);
}
__device__ __forceinline__ float bf2f(unsigned short s) {
    unsigned u = ((unsigned)s) << 16;
    return __builtin_bit_cast(float, u);
}

// ---------------- workspace layout ----------------
static constexpr size_t SZ_TREL = 51200ull * 128 * 4;
static constexpr size_t OFF_TREL = 0;
static constexpr size_t OFF_H    = OFF_TREL + SZ_TREL;
static constexpr size_t OFF_HP   = OFF_H + SZ_TREL;
static constexpr size_t OFF_SC   = OFF_HP + 40960ull * 128 * 4;
static constexpr size_t OFF_ES   = OFF_SC + 51200ull * 4;
static constexpr size_t OFF_ED   = OFF_ES + (size_t)NEDGE * 4;
static constexpr size_t OFF_EM   = OFF_ED + (size_t)NEDGE * 4;
static constexpr size_t OFF_Z    = OFF_EM + (size_t)NEDGE * 4;
static constexpr size_t OFF_COFF = OFF_Z + 128ull * 256 * 4;
static constexpr size_t OFF_CDEG = OFF_COFF + 51200ull * 4;
static constexpr size_t OFF_CSRC = OFF_CDEG + 51200ull * 4;
static constexpr size_t OFF_W1H  = OFF_CSRC + (size_t)NEDGE * 4;   // 16*13*512 shorts
static constexpr size_t OFF_W1L  = OFF_W1H + 16ull * 13 * 512 * 2;
static constexpr size_t OFF_W2H  = OFF_W1L + 16ull * 13 * 512 * 2;
static constexpr size_t OFF_W2L  = OFF_W2H + 16ull * 4 * 512 * 2;
static constexpr size_t OFF_W3H  = OFF_W2L + 16ull * 4 * 512 * 2;
static constexpr size_t OFF_W3L  = OFF_W3H + 16ull * 4 * 512 * 2;

// ---------------- weight split + fragment-tile prep (all 3 layers) ---------
// chunk[(n_tile*Ks + s)*512 + lane*8 + e] = B[n_tile*16 + (lane&15)][s*32 + (lane>>4)*8 + e]
__global__ __launch_bounds__(64) void prep_w_all(
    const float* __restrict__ Wrel1, const float* __restrict__ Wroot1,
    const float* __restrict__ Wrel2, const float* __restrict__ Wroot2,
    const float* __restrict__ Wrel3, const float* __restrict__ Wroot3,
    unsigned short* __restrict__ b1h, unsigned short* __restrict__ b1l,
    unsigned short* __restrict__ b2h, unsigned short* __restrict__ b2l,
    unsigned short* __restrict__ b3h, unsigned short* __restrict__ b3l) {
    const int layer = blockIdx.z;
    const int s = blockIdx.x;
    const int ntile = blockIdx.y;
    const int Ks = (layer == 0) ? 13 : 4;
    const int Kd = (layer == 0) ? F_IN : HD;
    if (s >= Ks) return;
    const float* Wrel  = (layer == 0) ? Wrel1  : (layer == 1) ? Wrel2  : Wrel3;
    const float* Wroot = (layer == 0) ? Wroot1 : (layer == 1) ? Wroot2 : Wroot3;
    unsigned short* bh = (layer == 0) ? b1h : (layer == 1) ? b2h : b3h;
    unsigned short* bl = (layer == 0) ? b1l : (layer == 1) ? b2l : b3l;
    const int t = threadIdx.x;
    const int rowin = t & 15, qd = t >> 4;
    const int n = ntile * 16 + rowin;
    const int k = s * 32 + qd * 8;
    const float* src = (n < 128) ? &Wrel[(n & 127) * Kd] : &Wroot[(n & 127) * Kd];
    unsigned short hv[8], lv[8];
#pragma unroll
    for (int e = 0; e < 8; e++) {
        float f = (k + e < Kd) ? src[k + e] : 0.f;
        unsigned short hi = f2bf(f);
        hv[e] = hi;
        lv[e] = f2bf(f - bf2f(hi));
    }
    size_t o = ((size_t)ntile * Ks + s) * 512 + (size_t)t * 8;
#pragma unroll
    for (int e = 0; e < 8; e++) { bh[o + e] = hv[e]; bl[o + e] = lv[e]; }
}

// ---------------- MFMA GEMM (bf16x3 split, no LDS, fully unrolled) --------
// Block 256 thr = 4 waves; wave w owns m-rows [bx*256+w*64, +64) (A read once);
// blockIdx.y picks 64-col n-slice (4 n-tiles); cols 0-127 -> t_rel, else h.
// Ks/Kd compile-time => full unroll => compiler pipelines loads with vmcnt(N).
template <int Ks, int Kd>
__global__ __launch_bounds__(256) void gemm_mfma(
    const float* __restrict__ A,
    const unsigned short* __restrict__ bh_p, const unsigned short* __restrict__ bl_p,
    float* __restrict__ t_rel, float* __restrict__ h) {
    const int tid = threadIdx.x;
    const int lane = tid & 63;
    const int wv = tid >> 6;
    const int lm = lane & 15;
    const int qd = (lane >> 4) & 3;
    const int m0 = blockIdx.x * 256 + wv * 64;
    const int nt0 = blockIdx.y * 4;

    f32x4 acc[4][4];
#pragma unroll
    for (int i = 0; i < 4; i++)
#pragma unroll
        for (int j = 0; j < 4; j++) acc[i][j] = (f32x4){0.f, 0.f, 0.f, 0.f};

    const float* Abase = A + (size_t)(m0 + lm) * Kd + qd * 8;

#pragma unroll
    for (int s = 0; s < Ks; s++) {
        // ---- A: direct fp32 frag loads + in-register split ----
        bf16x8 ah[4], al[4];
#pragma unroll
        for (int i = 0; i < 4; i++) {
            float4 f0, f1;
            if (s * 32 + qd * 8 < Kd) {
                const float* p = Abase + (size_t)i * 16 * Kd + s * 32;
                f0 = *(const float4*)p;
                f1 = *(const float4*)(p + 4);
            } else {
                f0 = make_float4(0.f, 0.f, 0.f, 0.f);
                f1 = f0;
            }
            float fe[8] = {f0.x, f0.y, f0.z, f0.w, f1.x, f1.y, f1.z, f1.w};
#pragma unroll
            for (int e = 0; e < 8; e++) {
                __bf16 hb = (__bf16)fe[e];
                ah[i][e] = hb;
                al[i][e] = (__bf16)(fe[e] - (float)hb);
            }
        }
        // ---- B: coalesced tiled frag loads (L1/L2-hot) ----
        bf16x8 bh[4], bl[4];
#pragma unroll
        for (int j = 0; j < 4; j++)
            bh[j] = *(const bf16x8*)&bh_p[((size_t)(nt0 + j) * Ks + s) * 512 + lane * 8];
#pragma unroll
        for (int j = 0; j < 4; j++)
            bl[j] = *(const bf16x8*)&bl_p[((size_t)(nt0 + j) * Ks + s) * 512 + lane * 8];
        // ---- MFMA: hi*hi + lo*hi + hi*lo ----
#pragma unroll
        for (int j = 0; j < 4; j++)
#pragma unroll
            for (int i = 0; i < 4; i++)
                acc[i][j] = __builtin_amdgcn_mfma_f32_16x16x32_bf16(
                    ah[i], bh[j], acc[i][j], 0, 0, 0);
#pragma unroll
        for (int j = 0; j < 4; j++)
#pragma unroll
            for (int i = 0; i < 4; i++)
                acc[i][j] = __builtin_amdgcn_mfma_f32_16x16x32_bf16(
                    al[i], bh[j], acc[i][j], 0, 0, 0);
#pragma unroll
        for (int j = 0; j < 4; j++)
#pragma unroll
            for (int i = 0; i < 4; i++)
                acc[i][j] = __builtin_amdgcn_mfma_f32_16x16x32_bf16(
                    ah[i], bl[j], acc[i][j], 0, 0, 0);
    }
    // ---- epilogue: C/D layout col=lane&15, row=qd*4+reg ----
    float* out = (blockIdx.y < 2) ? t_rel : h;
    const int colbase = (blockIdx.y & 1) * 64;
#pragma unroll
    for (int i = 0; i < 4; i++)
#pragma unroll
        for (int j = 0; j < 4; j++) {
            int row = m0 + i * 16 + qd * 4;
            int col = colbase + j * 16 + lm;
#pragma unroll
            for (int r = 0; r < 4; r++)
                out[(size_t)(row + r) * 128 + col] = acc[i][j][r];
        }
}

// ---------------- CSR build for layer 1 (original edges, no mask) ----------
__global__ __launch_bounds__(1024) void csr_build0(
    const int* __restrict__ gsrc, const int* __restrict__ gdst,
    int* __restrict__ csr_off, int* __restrict__ csr_deg, int* __restrict__ csr_src) {
    __shared__ int cnt[NPER];
    __shared__ int cur[NPER];
    __shared__ int sscan[512];
    const int g = blockIdx.x;
    const int t = threadIdx.x;
    for (int i = t; i < NPER; i += 1024) cnt[i] = 0;
    __syncthreads();
    for (int e = t; e < EPG; e += 1024) {
        int dl = gdst[g * EPG + e] - g * NPER;
        atomicAdd(&cnt[dl], 1);
    }
    __syncthreads();
    if (t < 512) sscan[t] = (t < NPER) ? cnt[t] : 0;
    __syncthreads();
    for (int d = 1; d < 512; d <<= 1) {
        int v = 0;
        if (t < 512 && t >= d) v = sscan[t - d];
        __syncthreads();
        if (t < 512 && t >= d) sscan[t] += v;
        __syncthreads();
    }
    if (t < NPER) {
        int excl = (t == 0) ? 0 : sscan[t - 1];
        int st = g * EPG + excl;
        csr_off[g * NPER + t] = st;
        csr_deg[g * NPER + t] = cnt[t];
        cur[t] = st;
    }
    __syncthreads();
    for (int e = t; e < EPG; e += 1024) {
        int eg = g * EPG + e;
        int dl = gdst[eg] - g * NPER;
        int slot = atomicAdd(&cur[dl], 1);
        csr_src[slot] = gsrc[eg];
    }
}

// ---------------- Aggregation (gather) + combine + relu + score ------------
__global__ __launch_bounds__(256) void agg_score(
    const float* __restrict__ t_rel,
    const int* __restrict__ csr_off, const int* __restrict__ csr_deg,
    const int* __restrict__ csr_src,
    const float* __restrict__ bias, const float* __restrict__ pw,
    float* __restrict__ h, float* __restrict__ sc, int npg) {
    const int xcd = blockIdx.x & 7;
    const int j = blockIdx.x >> 3;
    const int bpg = npg >> 2;
    const int graph = xcd * (BATCH / 8) + j / bpg;
    const int nblk = j - (j / bpg) * bpg;
    const int wid = graph * npg + nblk * 4 + (threadIdx.x >> 6);
    const int lane = threadIdx.x & 63;

    const int start = csr_off[wid];
    const int deg = csr_deg[wid];
    const size_t fo = (size_t)lane * 2;
    float a0 = 0.f, a1 = 0.f, b0 = 0.f, b1 = 0.f;
    float c0 = 0.f, c1 = 0.f, d0 = 0.f, d1 = 0.f;
    int e = 0;
    for (; e + 4 <= deg; e += 4) {
        int s0 = csr_src[start + e];
        int s1 = csr_src[start + e + 1];
        int s2 = csr_src[start + e + 2];
        int s3 = csr_src[start + e + 3];
        float2 v0 = *(const float2*)&t_rel[(size_t)s0 * 128 + fo];
        float2 v1 = *(const float2*)&t_rel[(size_t)s1 * 128 + fo];
        float2 v2 = *(const float2*)&t_rel[(size_t)s2 * 128 + fo];
        float2 v3 = *(const float2*)&t_rel[(size_t)s3 * 128 + fo];
        a0 += v0.x; a1 += v0.y;
        b0 += v1.x; b1 += v1.y;
        c0 += v2.x; c1 += v2.y;
        d0 += v3.x; d1 += v3.y;
    }
    for (; e < deg; e++) {
        int s0 = csr_src[start + e];
        float2 v0 = *(const float2*)&t_rel[(size_t)s0 * 128 + fo];
        a0 += v0.x; a1 += v0.y;
    }
    a0 += b0 + c0 + d0;
    a1 += b1 + c1 + d1;

    float2 bb = *(const float2*)&bias[fo];
    size_t o = (size_t)wid * 128 + fo;
    float2 hv = *(const float2*)&h[o];
    hv.x = fmaxf(hv.x + a0 + bb.x, 0.f);
    hv.y = fmaxf(hv.y + a1 + bb.y, 0.f);
    *(float2*)&h[o] = hv;
    float2 pp = *(const float2*)&pw[fo];
    float d = hv.x * pp.x + hv.y * pp.y;
    float nr = pp.x * pp.x + pp.y * pp.y;
#pragma unroll
    for (int off = 32; off; off >>= 1) {
        d += __shfl_down(d, off, 64);
        nr += __shfl_down(nr, off, 64);
    }
    if (lane == 0) sc[wid] = d / (sqrtf(nr) + 1e-16f);
}

// ---------------- fused topk + pool/readout + edge-remap/CSR ---------------
// One block per graph, 1024 threads. mode: 0=L1 (edges from gsrc/gdst),
// 1=L2 (edges from es/ed/em in-place), 2=L3 (no remap, no hp write).
__device__ __forceinline__ bool rank_before(float as, int ai, float bs, int bi) {
    return (as > bs) || (as == bs && ai < bi);
}
__global__ __launch_bounds__(1024) void topk_pool(
    const float* __restrict__ sc, const float* __restrict__ h,
    float* __restrict__ hp, float* __restrict__ z,
    const int* __restrict__ gsrc, const int* __restrict__ gdst,
    int* __restrict__ es, int* __restrict__ ed, int* __restrict__ em,
    int* __restrict__ csr_off, int* __restrict__ csr_deg, int* __restrict__ csr_src,
    int npg, int k, int mode) {
    __shared__ float sk[512];
    __shared__ int si[512];
    __shared__ int nid[NPER];
    __shared__ float tgs[K1];
    __shared__ int packed[EPG];
    __shared__ int cnt[K1];
    __shared__ int cur[K1];
    __shared__ int sscan[512];
    __shared__ float pmx[8][128], psm[8][128];
    const int g = blockIdx.x;
    const int t = threadIdx.x;

    // ---- phase 1: sort scores (desc, index tiebreak) ----
    if (t < 512) {
        sk[t] = (t < npg) ? sc[g * npg + t] : -INFINITY;
        si[t] = t;
    }
    __syncthreads();
    for (int size = 2; size <= 512; size <<= 1) {
        for (int stride = size >> 1; stride; stride >>= 1) {
            if (t < 512) {
                int i = t, j = i ^ stride;
                if (j > i) {
                    bool up = ((i & size) == 0);
                    float a = sk[i], b = sk[j];
                    int ai = si[i], bi = si[j];
                    bool doswap = up ? rank_before(b, bi, a, ai)
                                     : rank_before(a, ai, b, bi);
                    if (doswap) { sk[i] = b; sk[j] = a; si[i] = bi; si[j] = ai; }
                }
            }
            __syncthreads();
        }
    }
    // ---- phase 2: newid + tanh gates ----
    if (t < 512) {
        int orig = si[t];
        if (orig < npg) nid[orig] = (t < k) ? t : -1;
        if (t < k) tgs[t] = tanhf(sk[t]);
    }
    if (t < K1) cnt[t] = 0;
    __syncthreads();

    // ---- phase 3: pool + readout (+hp for next layer) ----
    {
        const int f = t & 127;
        const int jq = t >> 7;     // 0..7
        float mx = -INFINITY, sm = 0.f;
        for (int j = jq; j < k; j += 8) {
            float v = h[(size_t)(g * npg + si[j]) * 128 + f] * tgs[j];
            if (mode != 2) hp[(size_t)(g * k + j) * 128 + f] = v;
            mx = fmaxf(mx, v);
            sm += v;
        }
        pmx[jq][f] = mx; psm[jq][f] = sm;
        __syncthreads();
        if (t < 128) {
            mx = pmx[0][t]; sm = psm[0][t];
#pragma unroll
            for (int q = 1; q < 8; q++) {
                mx = fmaxf(mx, pmx[q][t]);
                sm += psm[q][t];
            }
            z[g * 256 + t] += mx;
            z[g * 256 + 128 + t] += sm / (float)k;
        }
    }
    if (mode == 2) return;

    // ---- phase 4: edge remap + CSR build over pooled node space ----
    for (int e = t; e < EPG; e += 1024) {
        int eg = g * EPG + e;
        int sl, dl, m;
        if (mode == 0) { sl = gsrc[eg] - g * NPER; dl = gdst[eg] - g * NPER; m = 1; }
        else           { sl = es[eg]; dl = ed[eg]; m = em[eg]; }
        int ns = nid[sl], nd = nid[dl];
        int keep = (m && ns >= 0 && nd >= 0) ? 1 : 0;
        es[eg] = keep ? ns : 0;
        ed[eg] = keep ? nd : 0;
        em[eg] = keep;
        packed[e] = keep ? (ns | (nd << 16)) : -1;
        if (keep) atomicAdd(&cnt[nd], 1);
    }
    __syncthreads();
    if (t < 512) sscan[t] = (t < k) ? cnt[t] : 0;
    __syncthreads();
    for (int d = 1; d < 512; d <<= 1) {
        int v = 0;
        if (t < 512 && t >= d) v = sscan[t - d];
        __syncthreads();
        if (t < 512 && t >= d) sscan[t] += v;
        __syncthreads();
    }
    if (t < k) {
        int excl = (t == 0) ? 0 : sscan[t - 1];
        int st = g * EPG + excl;
        csr_off[g * k + t] = st;
        csr_deg[g * k + t] = cnt[t];
        cur[t] = st;
    }
    __syncthreads();
    for (int e = t; e < EPG; e += 1024) {
        int p = packed[e];
        if (p >= 0) {
            int ns = p & 0xffff, nd = p >> 16;
            int slot = atomicAdd(&cur[nd], 1);
            csr_src[slot] = g * k + ns;
        }
    }
}

// ---------------- MLP head + log_softmax ----------------
__global__ __launch_bounds__(256) void mlp_head(const float* __restrict__ z,
                                                const float* __restrict__ W1,
                                                const float* __restrict__ bl1,
                                                const float* __restrict__ W2,
                                                const float* __restrict__ bl2,
                                                const float* __restrict__ W3,
                                                const float* __restrict__ bl3,
                                                float* __restrict__ out) {
    __shared__ float zs[256], l1[128], l2[64];
    const int g = blockIdx.x, t = threadIdx.x;
    zs[t] = z[g * 256 + t];
    __syncthreads();
    if (t < 128) {
        float s = bl1[t];
        const float* w = &W1[t * 256];
        for (int i = 0; i < 256; i++) s += w[i] * zs[i];
        l1[t] = fmaxf(s, 0.f);
    }
    __syncthreads();
    if (t < 64) {
        float s = bl2[t];
        const float* w = &W2[t * 128];
        for (int i = 0; i < 128; i++) s += w[i] * l1[i];
        l2[t] = fmaxf(s, 0.f);
    }
    __syncthreads();
    if (t == 0) {
        float a = bl3[0], b = bl3[1];
        for (int i = 0; i < 64; i++) { a += W3[i] * l2[i]; b += W3[64 + i] * l2[i]; }
        float m = fmaxf(a, b);
        float lse = m + logf(expf(a - m) + expf(b - m));
        out[g * 2 + 0] = a - lse;
        out[g * 2 + 1] = b - lse;
    }
}

// ---------------- launch ----------------
extern "C" void kernel_launch(void* const* d_in, const int* in_sizes, int n_in,
                              void* d_out, int out_size, void* d_ws, size_t ws_size,
                              hipStream_t stream) {
    const float* x        = (const float*)d_in[0];
    const int*   edge_src = (const int*)d_in[1];
    const int*   edge_dst = (const int*)d_in[2];
    const float* Wrel1 = (const float*)d_in[4];
    const float* Wroot1= (const float*)d_in[5];
    const float* b1    = (const float*)d_in[6];
    const float* pw1   = (const float*)d_in[7];
    const float* Wrel2 = (const float*)d_in[8];
    const float* Wroot2= (const float*)d_in[9];
    const float* b2    = (const float*)d_in[10];
    const float* pw2   = (const float*)d_in[11];
    const float* Wrel3 = (const float*)d_in[12];
    const float* Wroot3= (const float*)d_in[13];
    const float* b3    = (const float*)d_in[14];
    const float* pw3   = (const float*)d_in[15];
    const float* W1    = (const float*)d_in[16];
    const float* bl1   = (const float*)d_in[17];
    const float* W2    = (const float*)d_in[18];
    const float* bl2   = (const float*)d_in[19];
    const float* W3    = (const float*)d_in[20];
    const float* bl3   = (const float*)d_in[21];

    char* ws = (char*)d_ws;
    float* t_rel = (float*)(ws + OFF_TREL);
    float* h     = (float*)(ws + OFF_H);
    float* hp    = (float*)(ws + OFF_HP);
    float* sc    = (float*)(ws + OFF_SC);
    int*   es    = (int*)(ws + OFF_ES);
    int*   ed    = (int*)(ws + OFF_ED);
    int*   em    = (int*)(ws + OFF_EM);
    float* z     = (float*)(ws + OFF_Z);
    int*   coff  = (int*)(ws + OFF_COFF);
    int*   cdeg  = (int*)(ws + OFF_CDEG);
    int*   csrc  = (int*)(ws + OFF_CSRC);
    unsigned short* w1h = (unsigned short*)(ws + OFF_W1H);
    unsigned short* w1l = (unsigned short*)(ws + OFF_W1L);
    unsigned short* w2h = (unsigned short*)(ws + OFF_W2H);
    unsigned short* w2l = (unsigned short*)(ws + OFF_W2L);
    unsigned short* w3h = (unsigned short*)(ws + OFF_W3H);
    unsigned short* w3l = (unsigned short*)(ws + OFF_W3L);

    hipMemsetAsync(z, 0, 128ull * 256 * 4, stream);
    prep_w_all<<<dim3(13, 16, 3), 64, 0, stream>>>(
        Wrel1, Wroot1, Wrel2, Wroot2, Wrel3, Wroot3,
        w1h, w1l, w2h, w2l, w3h, w3l);
    csr_build0<<<BATCH, 1024, 0, stream>>>(edge_src, edge_dst, coff, cdeg, csrc);

    // ---------- layer 1 ----------
    gemm_mfma<13, F_IN><<<dim3(200, 4), 256, 0, stream>>>(x, w1h, w1l, t_rel, h);
    agg_score<<<51200 / 4, 256, 0, stream>>>(t_rel, coff, cdeg, csrc, b1, pw1,
                                             h, sc, NPER);
    topk_pool<<<BATCH, 1024, 0, stream>>>(sc, h, hp, z, edge_src, edge_dst,
                                          es, ed, em, coff, cdeg, csrc,
                                          NPER, K1, 0);

    // ---------- layer 2 ----------
    gemm_mfma<4, HD><<<dim3(160, 4), 256, 0, stream>>>(hp, w2h, w2l, t_rel, h);
    agg_score<<<40960 / 4, 256, 0, stream>>>(t_rel, coff, cdeg, csrc, b2, pw2,
                                             h, sc, K1);
    topk_pool<<<BATCH, 1024, 0, stream>>>(sc, h, hp, z, nullptr, nullptr,
                                          es, ed, em, coff, cdeg, csrc,
                                          K1, K2, 1);

    // ---------- layer 3 ----------
    gemm_mfma<4, HD><<<dim3(128, 4), 256, 0, stream>>>(hp, w3h, w3l, t_rel, h);
    agg_score<<<32768 / 4, 256, 0, stream>>>(t_rel, coff, cdeg, csrc, b3, pw3,
                                             h, sc, K2);
    topk_pool<<<BATCH, 1024, 0, stream>>>(sc, h, nullptr, z, nullptr, nullptr,
                                          es, ed, em, coff, cdeg, csrc,
                                          K2, K3, 2);

    // ---------- MLP head ----------
    mlp_head<<<BATCH, 256, 0, stream>>>(z, W1, bl1, W2, bl2, W3, bl3, (float*)d_out);
}

// Round 10
// 476.106 us; speedup vs baseline: 1.1437x; 1.0495x over previous
//
#include <hip/hip_runtime.h>
#include <math.h>

// Problem constants
#define BATCH 128
#define NPER 400
#define EPG 6400
#define NEDGE 819200
#define F_IN 400
#define HD 128
#define K1 320
#define K2 256
#define K3 205

typedef __bf16 bf16x8 __attribute__((ext_vector_type(8)));
typedef float f32x4 __attribute__((ext_vector_type(4)));

__device__ __forceinline__ unsigned short f2bf(float f) {
    unsigned u = __builtin_bit_cast(unsigned, f);
    unsigned r = u + 0x7fffu + ((u >> 16) & 1u);
    return (unsigned short)(r >> 16);
}
__device__ __forceinline__ float bf2f(unsigned short s) {
    unsigned u = ((unsigned)s) << 16;
    return __builtin_bit_cast(float, u);
}

// ---------------- workspace layout ----------------
static constexpr size_t SZ_TREL = 51200ull * 128 * 4;
static constexpr size_t OFF_TREL = 0;
static constexpr size_t OFF_H    = OFF_TREL + SZ_TREL;
static constexpr size_t OFF_HP   = OFF_H + SZ_TREL;
static constexpr size_t OFF_SC   = OFF_HP + 40960ull * 128 * 4;
static constexpr size_t OFF_ES   = OFF_SC + 51200ull * 4;
static constexpr size_t OFF_ED   = OFF_ES + (size_t)NEDGE * 4;
static constexpr size_t OFF_EM   = OFF_ED + (size_t)NEDGE * 4;
static constexpr size_t OFF_Z    = OFF_EM + (size_t)NEDGE * 4;
static constexpr size_t OFF_COFF = OFF_Z + 128ull * 256 * 4;
static constexpr size_t OFF_CDEG = OFF_COFF + 51200ull * 4;
static constexpr size_t OFF_CSRC = OFF_CDEG + 51200ull * 4;
static constexpr size_t OFF_W1H  = OFF_CSRC + (size_t)NEDGE * 4;   // 16*13*512 shorts
static constexpr size_t OFF_W1L  = OFF_W1H + 16ull * 13 * 512 * 2;
static constexpr size_t OFF_W2H  = OFF_W1L + 16ull * 13 * 512 * 2;
static constexpr size_t OFF_W2L  = OFF_W2H + 16ull * 4 * 512 * 2;
static constexpr size_t OFF_W3H  = OFF_W2L + 16ull * 4 * 512 * 2;
static constexpr size_t OFF_W3L  = OFF_W3H + 16ull * 4 * 512 * 2;

// ---------------- weight split + fragment-tile prep (all 3 layers) ---------
// chunk[(n_tile*Ks + s)*512 + lane*8 + e] = B[n_tile*16 + (lane&15)][s*32 + (lane>>4)*8 + e]
__global__ __launch_bounds__(64) void prep_w_all(
    const float* __restrict__ Wrel1, const float* __restrict__ Wroot1,
    const float* __restrict__ Wrel2, const float* __restrict__ Wroot2,
    const float* __restrict__ Wrel3, const float* __restrict__ Wroot3,
    unsigned short* __restrict__ b1h, unsigned short* __restrict__ b1l,
    unsigned short* __restrict__ b2h, unsigned short* __restrict__ b2l,
    unsigned short* __restrict__ b3h, unsigned short* __restrict__ b3l) {
    const int layer = blockIdx.z;
    const int s = blockIdx.x;
    const int ntile = blockIdx.y;
    const int Ks = (layer == 0) ? 13 : 4;
    const int Kd = (layer == 0) ? F_IN : HD;
    if (s >= Ks) return;
    const float* Wrel  = (layer == 0) ? Wrel1  : (layer == 1) ? Wrel2  : Wrel3;
    const float* Wroot = (layer == 0) ? Wroot1 : (layer == 1) ? Wroot2 : Wroot3;
    unsigned short* bh = (layer == 0) ? b1h : (layer == 1) ? b2h : b3h;
    unsigned short* bl = (layer == 0) ? b1l : (layer == 1) ? b2l : b3l;
    const int t = threadIdx.x;
    const int rowin = t & 15, qd = t >> 4;
    const int n = ntile * 16 + rowin;
    const int k = s * 32 + qd * 8;
    const float* src = (n < 128) ? &Wrel[(n & 127) * Kd] : &Wroot[(n & 127) * Kd];
    unsigned short hv[8], lv[8];
#pragma unroll
    for (int e = 0; e < 8; e++) {
        float f = (k + e < Kd) ? src[k + e] : 0.f;
        unsigned short hi = f2bf(f);
        hv[e] = hi;
        lv[e] = f2bf(f - bf2f(hi));
    }
    size_t o = ((size_t)ntile * Ks + s) * 512 + (size_t)t * 8;
#pragma unroll
    for (int e = 0; e < 8; e++) { bh[o + e] = hv[e]; bl[o + e] = lv[e]; }
}

// ---------------- MFMA GEMM (bf16x3 split, no LDS, unrolled, no A-redund) --
// 1-D grid M/64. Block 256 thr = 4 waves; all waves share the SAME 64 A-rows
// (L1-served, read once per block) and cover distinct 64-col n-slices
// (wave w -> n-tiles w*4..w*4+3). cols 0-127 -> t_rel, 128-255 -> h.
// Compile-time Ks => full unroll => cross-iteration load pipelining.
template <int Ks, int Kd>
__global__ __launch_bounds__(256) void gemm_mfma(
    const float* __restrict__ A,
    const unsigned short* __restrict__ bh_p, const unsigned short* __restrict__ bl_p,
    float* __restrict__ t_rel, float* __restrict__ h) {
    const int tid = threadIdx.x;
    const int lane = tid & 63;
    const int wv = tid >> 6;
    const int lm = lane & 15;
    const int qd = (lane >> 4) & 3;
    const int m0 = blockIdx.x * 64;
    const int nt0 = wv * 4;

    f32x4 acc[4][4];
#pragma unroll
    for (int i = 0; i < 4; i++)
#pragma unroll
        for (int j = 0; j < 4; j++) acc[i][j] = (f32x4){0.f, 0.f, 0.f, 0.f};

    const float* Abase = A + (size_t)(m0 + lm) * Kd + qd * 8;

#pragma unroll
    for (int s = 0; s < Ks; s++) {
        // ---- A: direct fp32 frag loads + in-register split ----
        bf16x8 ah[4], al[4];
#pragma unroll
        for (int i = 0; i < 4; i++) {
            float4 f0, f1;
            if (s * 32 + qd * 8 < Kd) {
                const float* p = Abase + (size_t)i * 16 * Kd + s * 32;
                f0 = *(const float4*)p;
                f1 = *(const float4*)(p + 4);
            } else {
                f0 = make_float4(0.f, 0.f, 0.f, 0.f);
                f1 = f0;
            }
            float fe[8] = {f0.x, f0.y, f0.z, f0.w, f1.x, f1.y, f1.z, f1.w};
#pragma unroll
            for (int e = 0; e < 8; e++) {
                __bf16 hb = (__bf16)fe[e];
                ah[i][e] = hb;
                al[i][e] = (__bf16)(fe[e] - (float)hb);
            }
        }
        // ---- B: coalesced tiled frag loads (L1/L2-hot) ----
        bf16x8 bh[4], bl[4];
#pragma unroll
        for (int j = 0; j < 4; j++)
            bh[j] = *(const bf16x8*)&bh_p[((size_t)(nt0 + j) * Ks + s) * 512 + lane * 8];
#pragma unroll
        for (int j = 0; j < 4; j++)
            bl[j] = *(const bf16x8*)&bl_p[((size_t)(nt0 + j) * Ks + s) * 512 + lane * 8];
        // ---- MFMA: hi*hi + lo*hi + hi*lo ----
#pragma unroll
        for (int j = 0; j < 4; j++)
#pragma unroll
            for (int i = 0; i < 4; i++)
                acc[i][j] = __builtin_amdgcn_mfma_f32_16x16x32_bf16(
                    ah[i], bh[j], acc[i][j], 0, 0, 0);
#pragma unroll
        for (int j = 0; j < 4; j++)
#pragma unroll
            for (int i = 0; i < 4; i++)
                acc[i][j] = __builtin_amdgcn_mfma_f32_16x16x32_bf16(
                    al[i], bh[j], acc[i][j], 0, 0, 0);
#pragma unroll
        for (int j = 0; j < 4; j++)
#pragma unroll
            for (int i = 0; i < 4; i++)
                acc[i][j] = __builtin_amdgcn_mfma_f32_16x16x32_bf16(
                    ah[i], bl[j], acc[i][j], 0, 0, 0);
    }
    // ---- epilogue: C/D layout col=lane&15, row=qd*4+reg ----
    float* out = (wv < 2) ? t_rel : h;
    const int colbase = (wv & 1) * 64;
#pragma unroll
    for (int i = 0; i < 4; i++)
#pragma unroll
        for (int j = 0; j < 4; j++) {
            int row = m0 + i * 16 + qd * 4;
            int col = colbase + j * 16 + lm;
#pragma unroll
            for (int r = 0; r < 4; r++)
                out[(size_t)(row + r) * 128 + col] = acc[i][j][r];
        }
}

// ---------------- CSR build for layer 1 (original edges, no mask) ----------
__global__ __launch_bounds__(1024) void csr_build0(
    const int* __restrict__ gsrc, const int* __restrict__ gdst,
    int* __restrict__ csr_off, int* __restrict__ csr_deg, int* __restrict__ csr_src) {
    __shared__ int cnt[NPER];
    __shared__ int cur[NPER];
    __shared__ int sscan[512];
    const int g = blockIdx.x;
    const int t = threadIdx.x;
    for (int i = t; i < NPER; i += 1024) cnt[i] = 0;
    __syncthreads();
    for (int e = t; e < EPG; e += 1024) {
        int dl = gdst[g * EPG + e] - g * NPER;
        atomicAdd(&cnt[dl], 1);
    }
    __syncthreads();
    if (t < 512) sscan[t] = (t < NPER) ? cnt[t] : 0;
    __syncthreads();
    for (int d = 1; d < 512; d <<= 1) {
        int v = 0;
        if (t < 512 && t >= d) v = sscan[t - d];
        __syncthreads();
        if (t < 512 && t >= d) sscan[t] += v;
        __syncthreads();
    }
    if (t < NPER) {
        int excl = (t == 0) ? 0 : sscan[t - 1];
        int st = g * EPG + excl;
        csr_off[g * NPER + t] = st;
        csr_deg[g * NPER + t] = cnt[t];
        cur[t] = st;
    }
    __syncthreads();
    for (int e = t; e < EPG; e += 1024) {
        int eg = g * EPG + e;
        int dl = gdst[eg] - g * NPER;
        int slot = atomicAdd(&cur[dl], 1);
        csr_src[slot] = gsrc[eg];
    }
}

// ---------------- Aggregation (gather) + combine + relu + score ------------
__global__ __launch_bounds__(256) void agg_score(
    const float* __restrict__ t_rel,
    const int* __restrict__ csr_off, const int* __restrict__ csr_deg,
    const int* __restrict__ csr_src,
    const float* __restrict__ bias, const float* __restrict__ pw,
    float* __restrict__ h, float* __restrict__ sc, int npg) {
    const int xcd = blockIdx.x & 7;
    const int j = blockIdx.x >> 3;
    const int bpg = npg >> 2;
    const int graph = xcd * (BATCH / 8) + j / bpg;
    const int nblk = j - (j / bpg) * bpg;
    const int wid = graph * npg + nblk * 4 + (threadIdx.x >> 6);
    const int lane = threadIdx.x & 63;

    const int start = csr_off[wid];
    const int deg = csr_deg[wid];
    const size_t fo = (size_t)lane * 2;
    float a0 = 0.f, a1 = 0.f, b0 = 0.f, b1 = 0.f;
    float c0 = 0.f, c1 = 0.f, d0 = 0.f, d1 = 0.f;
    int e = 0;
    for (; e + 4 <= deg; e += 4) {
        int s0 = csr_src[start + e];
        int s1 = csr_src[start + e + 1];
        int s2 = csr_src[start + e + 2];
        int s3 = csr_src[start + e + 3];
        float2 v0 = *(const float2*)&t_rel[(size_t)s0 * 128 + fo];
        float2 v1 = *(const float2*)&t_rel[(size_t)s1 * 128 + fo];
        float2 v2 = *(const float2*)&t_rel[(size_t)s2 * 128 + fo];
        float2 v3 = *(const float2*)&t_rel[(size_t)s3 * 128 + fo];
        a0 += v0.x; a1 += v0.y;
        b0 += v1.x; b1 += v1.y;
        c0 += v2.x; c1 += v2.y;
        d0 += v3.x; d1 += v3.y;
    }
    for (; e < deg; e++) {
        int s0 = csr_src[start + e];
        float2 v0 = *(const float2*)&t_rel[(size_t)s0 * 128 + fo];
        a0 += v0.x; a1 += v0.y;
    }
    a0 += b0 + c0 + d0;
    a1 += b1 + c1 + d1;

    float2 bb = *(const float2*)&bias[fo];
    size_t o = (size_t)wid * 128 + fo;
    float2 hv = *(const float2*)&h[o];
    hv.x = fmaxf(hv.x + a0 + bb.x, 0.f);
    hv.y = fmaxf(hv.y + a1 + bb.y, 0.f);
    *(float2*)&h[o] = hv;
    float2 pp = *(const float2*)&pw[fo];
    float d = hv.x * pp.x + hv.y * pp.y;
    float nr = pp.x * pp.x + pp.y * pp.y;
#pragma unroll
    for (int off = 32; off; off >>= 1) {
        d += __shfl_down(d, off, 64);
        nr += __shfl_down(nr, off, 64);
    }
    if (lane == 0) sc[wid] = d / (sqrtf(nr) + 1e-16f);
}

// ---------------- fused topk + pool/readout + edge-remap/CSR ---------------
// One block per graph, 1024 threads. mode: 0=L1 (edges from gsrc/gdst),
// 1=L2 (edges from es/ed/em in-place), 2=L3 (no remap, no hp write).
__device__ __forceinline__ bool rank_before(float as, int ai, float bs, int bi) {
    return (as > bs) || (as == bs && ai < bi);
}
__global__ __launch_bounds__(1024) void topk_pool(
    const float* __restrict__ sc, const float* __restrict__ h,
    float* __restrict__ hp, float* __restrict__ z,
    const int* __restrict__ gsrc, const int* __restrict__ gdst,
    int* __restrict__ es, int* __restrict__ ed, int* __restrict__ em,
    int* __restrict__ csr_off, int* __restrict__ csr_deg, int* __restrict__ csr_src,
    int npg, int k, int mode) {
    __shared__ float sk[512];
    __shared__ int si[512];
    __shared__ int nid[NPER];
    __shared__ float tgs[K1];
    __shared__ int packed[EPG];
    __shared__ int cnt[K1];
    __shared__ int cur[K1];
    __shared__ int sscan[512];
    __shared__ float pmx[8][128], psm[8][128];
    const int g = blockIdx.x;
    const int t = threadIdx.x;

    // ---- phase 1: sort scores (desc, index tiebreak) ----
    if (t < 512) {
        sk[t] = (t < npg) ? sc[g * npg + t] : -INFINITY;
        si[t] = t;
    }
    __syncthreads();
    for (int size = 2; size <= 512; size <<= 1) {
        for (int stride = size >> 1; stride; stride >>= 1) {
            if (t < 512) {
                int i = t, j = i ^ stride;
                if (j > i) {
                    bool up = ((i & size) == 0);
                    float a = sk[i], b = sk[j];
                    int ai = si[i], bi = si[j];
                    bool doswap = up ? rank_before(b, bi, a, ai)
                                     : rank_before(a, ai, b, bi);
                    if (doswap) { sk[i] = b; sk[j] = a; si[i] = bi; si[j] = ai; }
                }
            }
            __syncthreads();
        }
    }
    // ---- phase 2: newid + tanh gates ----
    if (t < 512) {
        int orig = si[t];
        if (orig < npg) nid[orig] = (t < k) ? t : -1;
        if (t < k) tgs[t] = tanhf(sk[t]);
    }
    if (t < K1) cnt[t] = 0;
    __syncthreads();

    // ---- phase 3: pool + readout (+hp for next layer) ----
    {
        const int f = t & 127;
        const int jq = t >> 7;     // 0..7
        float mx = -INFINITY, sm = 0.f;
        for (int j = jq; j < k; j += 8) {
            float v = h[(size_t)(g * npg + si[j]) * 128 + f] * tgs[j];
            if (mode != 2) hp[(size_t)(g * k + j) * 128 + f] = v;
            mx = fmaxf(mx, v);
            sm += v;
        }
        pmx[jq][f] = mx; psm[jq][f] = sm;
        __syncthreads();
        if (t < 128) {
            mx = pmx[0][t]; sm = psm[0][t];
#pragma unroll
            for (int q = 1; q < 8; q++) {
                mx = fmaxf(mx, pmx[q][t]);
                sm += psm[q][t];
            }
            z[g * 256 + t] += mx;
            z[g * 256 + 128 + t] += sm / (float)k;
        }
    }
    if (mode == 2) return;

    // ---- phase 4: edge remap + CSR build over pooled node space ----
    for (int e = t; e < EPG; e += 1024) {
        int eg = g * EPG + e;
        int sl, dl, m;
        if (mode == 0) { sl = gsrc[eg] - g * NPER; dl = gdst[eg] - g * NPER; m = 1; }
        else           { sl = es[eg]; dl = ed[eg]; m = em[eg]; }
        int ns = nid[sl], nd = nid[dl];
        int keep = (m && ns >= 0 && nd >= 0) ? 1 : 0;
        es[eg] = keep ? ns : 0;
        ed[eg] = keep ? nd : 0;
        em[eg] = keep;
        packed[e] = keep ? (ns | (nd << 16)) : -1;
        if (keep) atomicAdd(&cnt[nd], 1);
    }
    __syncthreads();
    if (t < 512) sscan[t] = (t < k) ? cnt[t] : 0;
    __syncthreads();
    for (int d = 1; d < 512; d <<= 1) {
        int v = 0;
        if (t < 512 && t >= d) v = sscan[t - d];
        __syncthreads();
        if (t < 512 && t >= d) sscan[t] += v;
        __syncthreads();
    }
    if (t < k) {
        int excl = (t == 0) ? 0 : sscan[t - 1];
        int st = g * EPG + excl;
        csr_off[g * k + t] = st;
        csr_deg[g * k + t] = cnt[t];
        cur[t] = st;
    }
    __syncthreads();
    for (int e = t; e < EPG; e += 1024) {
        int p = packed[e];
        if (p >= 0) {
            int ns = p & 0xffff, nd = p >> 16;
            int slot = atomicAdd(&cur[nd], 1);
            csr_src[slot] = g * k + ns;
        }
    }
}

// ---------------- MLP head + log_softmax ----------------
__global__ __launch_bounds__(256) void mlp_head(const float* __restrict__ z,
                                                const float* __restrict__ W1,
                                                const float* __restrict__ bl1,
                                                const float* __restrict__ W2,
                                                const float* __restrict__ bl2,
                                                const float* __restrict__ W3,
                                                const float* __restrict__ bl3,
                                                float* __restrict__ out) {
    __shared__ float zs[256], l1[128], l2[64];
    const int g = blockIdx.x, t = threadIdx.x;
    zs[t] = z[g * 256 + t];
    __syncthreads();
    if (t < 128) {
        float s = bl1[t];
        const float* w = &W1[t * 256];
        for (int i = 0; i < 256; i++) s += w[i] * zs[i];
        l1[t] = fmaxf(s, 0.f);
    }
    __syncthreads();
    if (t < 64) {
        float s = bl2[t];
        const float* w = &W2[t * 128];
        for (int i = 0; i < 128; i++) s += w[i] * l1[i];
        l2[t] = fmaxf(s, 0.f);
    }
    __syncthreads();
    if (t == 0) {
        float a = bl3[0], b = bl3[1];
        for (int i = 0; i < 64; i++) { a += W3[i] * l2[i]; b += W3[64 + i] * l2[i]; }
        float m = fmaxf(a, b);
        float lse = m + logf(expf(a - m) + expf(b - m));
        out[g * 2 + 0] = a - lse;
        out[g * 2 + 1] = b - lse;
    }
}

// ---------------- launch ----------------
extern "C" void kernel_launch(void* const* d_in, const int* in_sizes, int n_in,
                              void* d_out, int out_size, void* d_ws, size_t ws_size,
                              hipStream_t stream) {
    const float* x        = (const float*)d_in[0];
    const int*   edge_src = (const int*)d_in[1];
    const int*   edge_dst = (const int*)d_in[2];
    const float* Wrel1 = (const float*)d_in[4];
    const float* Wroot1= (const float*)d_in[5];
    const float* b1    = (const float*)d_in[6];
    const float* pw1   = (const float*)d_in[7];
    const float* Wrel2 = (const float*)d_in[8];
    const float* Wroot2= (const float*)d_in[9];
    const float* b2    = (const float*)d_in[10];
    const float* pw2   = (const float*)d_in[11];
    const float* Wrel3 = (const float*)d_in[12];
    const float* Wroot3= (const float*)d_in[13];
    const float* b3    = (const float*)d_in[14];
    const float* pw3   = (const float*)d_in[15];
    const float* W1    = (const float*)d_in[16];
    const float* bl1   = (const float*)d_in[17];
    const float* W2    = (const float*)d_in[18];
    const float* bl2   = (const float*)d_in[19];
    const float* W3    = (const float*)d_in[20];
    const float* bl3   = (const float*)d_in[21];

    char* ws = (char*)d_ws;
    float* t_rel = (float*)(ws + OFF_TREL);
    float* h     = (float*)(ws + OFF_H);
    float* hp    = (float*)(ws + OFF_HP);
    float* sc    = (float*)(ws + OFF_SC);
    int*   es    = (int*)(ws + OFF_ES);
    int*   ed    = (int*)(ws + OFF_ED);
    int*   em    = (int*)(ws + OFF_EM);
    float* z     = (float*)(ws + OFF_Z);
    int*   coff  = (int*)(ws + OFF_COFF);
    int*   cdeg  = (int*)(ws + OFF_CDEG);
    int*   csrc  = (int*)(ws + OFF_CSRC);
    unsigned short* w1h = (unsigned short*)(ws + OFF_W1H);
    unsigned short* w1l = (unsigned short*)(ws + OFF_W1L);
    unsigned short* w2h = (unsigned short*)(ws + OFF_W2H);
    unsigned short* w2l = (unsigned short*)(ws + OFF_W2L);
    unsigned short* w3h = (unsigned short*)(ws + OFF_W3H);
    unsigned short* w3l = (unsigned short*)(ws + OFF_W3L);

    hipMemsetAsync(z, 0, 128ull * 256 * 4, stream);
    prep_w_all<<<dim3(13, 16, 3), 64, 0, stream>>>(
        Wrel1, Wroot1, Wrel2, Wroot2, Wrel3, Wroot3,
        w1h, w1l, w2h, w2l, w3h, w3l);
    csr_build0<<<BATCH, 1024, 0, stream>>>(edge_src, edge_dst, coff, cdeg, csrc);

    // ---------- layer 1 ----------
    gemm_mfma<13, F_IN><<<800, 256, 0, stream>>>(x, w1h, w1l, t_rel, h);
    agg_score<<<51200 / 4, 256, 0, stream>>>(t_rel, coff, cdeg, csrc, b1, pw1,
                                             h, sc, NPER);
    topk_pool<<<BATCH, 1024, 0, stream>>>(sc, h, hp, z, edge_src, edge_dst,
                                          es, ed, em, coff, cdeg, csrc,
                                          NPER, K1, 0);

    // ---------- layer 2 ----------
    gemm_mfma<4, HD><<<640, 256, 0, stream>>>(hp, w2h, w2l, t_rel, h);
    agg_score<<<40960 / 4, 256, 0, stream>>>(t_rel, coff, cdeg, csrc, b2, pw2,
                                             h, sc, K1);
    topk_pool<<<BATCH, 1024, 0, stream>>>(sc, h, hp, z, nullptr, nullptr,
                                          es, ed, em, coff, cdeg, csrc,
                                          K1, K2, 1);

    // ---------- layer 3 ----------
    gemm_mfma<4, HD><<<512, 256, 0, stream>>>(hp, w3h, w3l, t_rel, h);
    agg_score<<<32768 / 4, 256, 0, stream>>>(t_rel, coff, cdeg, csrc, b3, pw3,
                                             h, sc, K2);
    topk_pool<<<BATCH, 1024, 0, stream>>>(sc, h, nullptr, z, nullptr, nullptr,
                                          es, ed, em, coff, cdeg, csrc,
                                          K2, K3, 2);

    // ---------- MLP head ----------
    mlp_head<<<BATCH, 256, 0, stream>>>(z, W1, bl1, W2, bl2, W3, bl3, (float*)d_out);
}